// Round 11
// baseline (160.215 us; speedup 1.0000x reference)
//
#include <hip/hip_runtime.h>
#include <hip/hip_bf16.h>

#define BATCH   32768
#define DIM     2048
#define NHEADS  28
#define NCOLS   280
#define LOSS_SCALE (1.0f / (float)(BATCH * NHEADS))

typedef __attribute__((ext_vector_type(8))) short short8;
typedef __attribute__((ext_vector_type(4))) float f32x4;
typedef __attribute__((ext_vector_type(16))) float f32x16;

__device__ __forceinline__ short f2bf(float f) {
    union { __hip_bfloat16 h; short s; } u; u.h = __float2bfloat16(f); return u.s;
}

// ---------------------------------------------------------------------------
// W pre-swizzle: W [280][2048] f32 -> Wswz bf16 in 32x32x16 B-frag order,
// K-tile-major: short idx = kt*10240 + ((nt*2+ks)*64 + l)*8 + j
//   n = nt*32 + (l&31), k = kt*32 + ks*16 + (l>>5)*8 + j
// ---------------------------------------------------------------------------
__global__ void mvh_swz(const float* __restrict__ W, short* __restrict__ Wswz) {
    int t = blockIdx.x * 256 + threadIdx.x;      // 81920 threads (320 blocks)
    int kt = t / 1280;
    int r  = t - kt * 1280;
    int F  = r >> 6;                             // 0..19
    int nt = F >> 1;
    int ks = F & 1;
    int l  = t & 63;
    int n = nt * 32 + (l & 31);
    int k = kt * 32 + ks * 16 + (l >> 5) * 8;
    short8 v;
    #pragma unroll
    for (int j = 0; j < 8; j++) v[j] = 0;
    if (n < NCOLS) {
        const float* src = W + (size_t)n * DIM + k;
        #pragma unroll
        for (int j = 0; j < 8; j++) v[j] = f2bf(src[j]);
    }
    *(short8*)(Wswz + (size_t)t * 8) = v;
}

// ---------------------------------------------------------------------------
// GEMM: logits[b][n] = sum_d hidden[b][d]*W[n][d] + bias[n]
// grid 512 x 256 threads (4 waves: wsub=w>>1 x nh=w&1), 2 blocks/CU.
// BM=64, BK=32, MFMA 32x32x16, N padded 320. acc = 5 x f32x16 per wave.
// B: NO LDS — 10 short8 reg-loads per wave per tile from L2-resident Wswz.
// A: only LDS stream. Staged per 2-tile PHASE (8KB bf16 frag-major):
//    thread loads 64B contiguous fp32 (full L2 lines), cvt, 2 ds_write_b128.
//    Double-buffered, ONE raw s_barrier per phase, lgkmcnt(0) only —
//    vmcnt NEVER drained; A(p+2) issued after B loads (SB0-pinned) so
//    in-order retirement never makes a B-use wait on HBM.
// ---------------------------------------------------------------------------
#define SB0() __builtin_amdgcn_sched_barrier(0)
#define BAR() do { SB0(); asm volatile("s_waitcnt lgkmcnt(0)" ::: "memory"); \
    __builtin_amdgcn_s_barrier(); SB0(); } while (0)

__global__ __launch_bounds__(256, 2)
void mvh_gemm(const float* __restrict__ hidden, const short* __restrict__ Wswz,
              const float* __restrict__ bias, float* __restrict__ logits) {
    __shared__ __align__(16) char lds[16384];    // 2 phase-buffers x 8KB

    const int tid  = threadIdx.x;
    const int lane = tid & 63;
    const int wave = tid >> 6;          // 0..3
    const int wsub = wave >> 1;         // 32-row frag
    const int nh   = wave & 1;          // 5-frag col half
    const int rowbase = blockIdx.x * 64;

    // A staging: thread t: row srow=t>>2, k-chunk skc=t&3 (16 floats = 64B).
    const int srow = tid >> 2;
    const int skc  = tid & 3;
    const float* gA = hidden + (size_t)(rowbase + srow) * DIM + skc * 16;
    // frag-major dest: tile=skc>>1, ks=skc&1, frag=(srow>>5)*2+ks,
    // lane' = (srow&31) + 32*h (h = k-octet), 16B each.
    const int aw0 = (skc >> 1) * 4096 + ((srow >> 5) * 2 + (skc & 1)) * 1024
                  + (srow & 31) * 16;

    f32x16 acc[5];
    #pragma unroll
    for (int nf = 0; nf < 5; nf++)
        #pragma unroll
        for (int r = 0; r < 16; r++) acc[nf][r] = 0.0f;

    short8 b[10];
    f32x4 gx0, gx1, gx2, gx3;   // A-inflight slot (even phases)
    f32x4 gy0, gy1, gy2, gy3;   // A-inflight slot (odd phases)

#define LOADA(r0, r1, r2, r3, ph) do { \
    const float* p_ = gA + (size_t)(ph) * 64; \
    r0 = *(const f32x4*)(p_);      r1 = *(const f32x4*)(p_ + 4); \
    r2 = *(const f32x4*)(p_ + 8);  r3 = *(const f32x4*)(p_ + 12); \
} while (0)

#define WRITEA(buf, r0, r1, r2, r3) do { \
    short8 lo_, hi_; \
    _Pragma("unroll") \
    for (int j_ = 0; j_ < 4; j_++) { \
        lo_[j_] = f2bf(r0[j_]); lo_[4 + j_] = f2bf(r1[j_]); \
        hi_[j_] = f2bf(r2[j_]); hi_[4 + j_] = f2bf(r3[j_]); \
    } \
    *(short8*)(lds + (buf) * 8192 + aw0)       = lo_; \
    *(short8*)(lds + (buf) * 8192 + aw0 + 512) = hi_; \
} while (0)

#define LOADB(kt) do { \
    _Pragma("unroll") \
    for (int q_ = 0; q_ < 10; q_++) \
        b[q_] = *(const short8*)(Wswz + (size_t)(kt) * 10240 \
                 + (((nh * 5 + (q_ >> 1)) * 2 + (q_ & 1)) * 64 + lane) * 8); \
} while (0)

#define COMPUTE(buf, tile) do { \
    _Pragma("unroll") \
    for (int ks_ = 0; ks_ < 2; ks_++) { \
        short8 af_ = *(const short8*)(lds + (buf) * 8192 + (tile) * 4096 \
                      + (wsub * 2 + ks_) * 1024 + lane * 16); \
        _Pragma("unroll") \
        for (int nf_ = 0; nf_ < 5; nf_++) \
            acc[nf_] = __builtin_amdgcn_mfma_f32_32x32x16_bf16(af_, b[nf_ * 2 + ks_], acc[nf_], 0, 0, 0); \
    } \
} while (0)

    // ---- prologue: B(0); A phase0 -> buf0; A phase1 -> gy regs ----
    LOADB(0);
    LOADA(gx0, gx1, gx2, gx3, 0);
    LOADA(gy0, gy1, gy2, gy3, 1);
    WRITEA(0, gx0, gx1, gx2, gx3);   // compiler waits A(0) regs only
    BAR();

    // ---- main: 15 double-phase iters (p = 0..29) + tail p=30,31 ----
    #pragma unroll 1
    for (int pp = 0; pp < 15; pp++) {
        const int p = pp * 2;
        // even phase p (buffer 0): tiles 2p, 2p+1
        COMPUTE(0, 0);
        LOADB(2 * p + 1);
        COMPUTE(0, 1);
        LOADB(2 * p + 2);
        SB0();                               // pin: A loads stay AFTER B loads
        WRITEA(1, gy0, gy1, gy2, gy3);       // phase p+1 -> buf1
        LOADA(gx0, gx1, gx2, gx3, p + 2);
        BAR();
        // odd phase p+1 (buffer 1): tiles 2p+2, 2p+3
        COMPUTE(1, 0);
        LOADB(2 * p + 3);
        COMPUTE(1, 1);
        LOADB(2 * p + 4);
        SB0();
        WRITEA(0, gx0, gx1, gx2, gx3);       // phase p+2 -> buf0
        LOADA(gy0, gy1, gy2, gy3, p + 3);
        BAR();
    }
    // phase 30 (buffer 0): tiles 60, 61
    COMPUTE(0, 0);
    LOADB(61);
    COMPUTE(0, 1);
    LOADB(62);
    SB0();
    WRITEA(1, gy0, gy1, gy2, gy3);           // phase 31 -> buf1
    BAR();
    // phase 31 (buffer 1): tiles 62, 63
    COMPUTE(1, 0);
    LOADB(63);
    COMPUTE(1, 1);

#undef LOADA
#undef WRITEA
#undef LOADB
#undef COMPUTE

    // ---- epilogue: bias + store ----
    // C/D 32x32: col = lane&31, row = (r&3) + 8*(r>>2) + 4*(lane>>5)
    #pragma unroll
    for (int nf = 0; nf < 5; nf++) {
        int c = (nh * 5 + nf) * 32 + (lane & 31);
        if (c < NCOLS) {
            float bv = bias[c];
            #pragma unroll
            for (int r = 0; r < 16; r++) {
                int row = rowbase + wsub * 32 + (r & 3) + 8 * (r >> 2) + 4 * (lane >> 5);
                logits[(size_t)row * NCOLS + c] = acc[nf][r] + bv;
            }
        }
    }
}

// ---------------------------------------------------------------------------
// Loss: one thread per (row, head). nll = logsumexp(10) - x[label].
// ---------------------------------------------------------------------------
__global__ __launch_bounds__(256)
void mvh_loss(const float* __restrict__ logits, const int* __restrict__ labels,
              float* __restrict__ loss_out) {
    int gid = blockIdx.x * 256 + threadIdx.x;    // 917504 = 3584*256 exactly
    const float* p = logits + (size_t)gid * 10;
    float x[10];
    #pragma unroll
    for (int j = 0; j < 10; j++) x[j] = p[j];
    float m = x[0];
    #pragma unroll
    for (int j = 1; j < 10; j++) m = fmaxf(m, x[j]);
    float s = 0.0f;
    #pragma unroll
    for (int j = 0; j < 10; j++) s += __expf(x[j] - m);
    int lab = labels[gid];
    float xl = x[0];
    #pragma unroll
    for (int j = 1; j < 10; j++) xl = (lab == j) ? x[j] : xl;
    float nll = m + __logf(s) - xl;

    #pragma unroll
    for (int off = 32; off > 0; off >>= 1)
        nll += __shfl_down(nll, off, 64);

    __shared__ float part[4];
    int lane = threadIdx.x & 63, wv = threadIdx.x >> 6;
    if (lane == 0) part[wv] = nll;
    __syncthreads();
    if (threadIdx.x == 0)
        atomicAdd(loss_out, (part[0] + part[1] + part[2] + part[3]) * LOSS_SCALE);
}

extern "C" void kernel_launch(void* const* d_in, const int* in_sizes, int n_in,
                              void* d_out, int out_size, void* d_ws, size_t ws_size,
                              hipStream_t stream) {
    const float* hidden = (const float*)d_in[0];
    const int* labels   = (const int*)d_in[1];
    const float* W      = (const float*)d_in[2];
    const float* bias   = (const float*)d_in[3];
    float* out = (float*)d_out;
    short* Wswz = (short*)d_ws;   // 655360 bf16 = 1.31 MB

    (void)hipMemsetAsync(d_out, 0, sizeof(float), stream);     // zero loss accumulator
    mvh_swz<<<320, 256, 0, stream>>>(W, Wswz);
    mvh_gemm<<<512, 256, 0, stream>>>(hidden, Wswz, bias, out + 1);
    mvh_loss<<<3584, 256, 0, stream>>>(out + 1, labels, out);
}